// Round 2
// baseline (247.255 us; speedup 1.0000x reference)
//
#include <hip/hip_runtime.h>

// VQ-VAE vector quantizer forward, MI355X.
// inputs:  d_in[0] = inputs  f32 [32, 64, 64, 64]  (B, C, H, W), C = embedding dim
//          d_in[1] = codebook f32 [512, 64]
// output:  d_out = quantized_st f32 [32,64,64,64] (== quantized numerically),
//          then d_out[8388608] = loss scalar.

#define NUM_EMB 512
#define DIM     64
#define HW      4096          // 64*64
#define NPIX    131072        // 32*4096
#define BLOCK   256
#define NBLK    (NPIX / BLOCK)  // 512
#define NELEM   8388608.0f    // NPIX*DIM

__global__ __launch_bounds__(BLOCK, 2) void vq_main(
    const float* __restrict__ x, const float* __restrict__ cb,
    float* __restrict__ out, float* __restrict__ blocksum)
{
    __shared__ float en2[NUM_EMB];
    __shared__ float wsum[BLOCK / 64];

    // --- codebook squared norms, cooperatively, once per block (cheap) ---
    for (int k = threadIdx.x; k < NUM_EMB; k += BLOCK) {
        const float4* row = (const float4*)(cb + k * DIM);
        float s = 0.f;
#pragma unroll
        for (int c4 = 0; c4 < DIM / 4; ++c4) {
            float4 e = row[c4];
            s += e.x * e.x + e.y * e.y + e.z * e.z + e.w * e.w;
        }
        en2[k] = s;
    }
    __syncthreads();

    // --- load this thread's pixel vector into registers (coalesced per-wave) ---
    const int p  = blockIdx.x * BLOCK + threadIdx.x;   // pixel id
    const int b  = p >> 12;                            // p / 4096
    const int hw = p & 4095;
    const float* xp = x + (size_t)b * (DIM * HW) + hw;

    float xr[DIM];
#pragma unroll
    for (int c = 0; c < DIM; ++c)
        xr[c] = xp[(size_t)c * HW];

    float xsq = 0.f;
#pragma unroll
    for (int c = 0; c < DIM; ++c)
        xsq += xr[c] * xr[c];

    // --- argmin over 512 codebook entries ---
    float best = 3.4e38f;
    int   bidx = 0;
    for (int k = 0; k < NUM_EMB; ++k) {
        const float4* row = (const float4*)(cb + k * DIM);
        float d0 = 0.f, d1 = 0.f, d2 = 0.f, d3 = 0.f;   // 4 indep FMA chains
#pragma unroll
        for (int c4 = 0; c4 < DIM / 4; ++c4) {
            float4 e = row[c4];
            d0 = fmaf(xr[4 * c4 + 0], e.x, d0);
            d1 = fmaf(xr[4 * c4 + 1], e.y, d1);
            d2 = fmaf(xr[4 * c4 + 2], e.z, d2);
            d3 = fmaf(xr[4 * c4 + 3], e.w, d3);
        }
        const float dot = (d0 + d1) + (d2 + d3);
        // match reference rounding: (xsq - 2*dot) rounds once (2*dot exact),
        // then + ||e||^2 rounds once.
        const float dist = fmaf(-2.f, dot, xsq) + en2[k];
        if (dist < best) { best = dist; bidx = k; }   // strict <: first-min wins, like argmin
    }

    // --- epilogue: gather winning row, write quantized_st, accumulate loss ---
    const float4* qrow = (const float4*)(cb + bidx * DIM);
    float* op = out + (size_t)b * (DIM * HW) + hw;
    float lsum = 0.f;
#pragma unroll
    for (int c4 = 0; c4 < DIM / 4; ++c4) {
        float4 e = qrow[c4];
        float dx0 = e.x - xr[4 * c4 + 0];
        float dx1 = e.y - xr[4 * c4 + 1];
        float dx2 = e.z - xr[4 * c4 + 2];
        float dx3 = e.w - xr[4 * c4 + 3];
        op[(size_t)(4 * c4 + 0) * HW] = xr[4 * c4 + 0] + dx0;  // x + (q-x), like the reference ST
        op[(size_t)(4 * c4 + 1) * HW] = xr[4 * c4 + 1] + dx1;
        op[(size_t)(4 * c4 + 2) * HW] = xr[4 * c4 + 2] + dx2;
        op[(size_t)(4 * c4 + 3) * HW] = xr[4 * c4 + 3] + dx3;
        lsum = fmaf(dx0, dx0, lsum);
        lsum = fmaf(dx1, dx1, lsum);
        lsum = fmaf(dx2, dx2, lsum);
        lsum = fmaf(dx3, dx3, lsum);
    }

    // --- block reduction of squared-error sum ---
#pragma unroll
    for (int off = 32; off > 0; off >>= 1)
        lsum += __shfl_xor(lsum, off);
    const int wid = threadIdx.x >> 6;
    if ((threadIdx.x & 63) == 0) wsum[wid] = lsum;
    __syncthreads();
    if (threadIdx.x == 0)
        blocksum[blockIdx.x] = (wsum[0] + wsum[1]) + (wsum[2] + wsum[3]);
}

__global__ void vq_final(const float* __restrict__ bs, float* __restrict__ lossp)
{
    float v = bs[threadIdx.x];          // 512 threads, one partial each
#pragma unroll
    for (int off = 32; off > 0; off >>= 1)
        v += __shfl_xor(v, off);
    __shared__ float ws[8];
    const int wid = threadIdx.x >> 6;
    if ((threadIdx.x & 63) == 0) ws[wid] = v;
    __syncthreads();
    if (threadIdx.x == 0) {
        float s = 0.f;
#pragma unroll
        for (int i = 0; i < 8; ++i) s += ws[i];
        const float L = s / NELEM;       // mean squared error (== both loss terms)
        *lossp = L + 0.25f * L;          // q_latent + commitment*e_latent
    }
}

extern "C" void kernel_launch(void* const* d_in, const int* in_sizes, int n_in,
                              void* d_out, int out_size, void* d_ws, size_t ws_size,
                              hipStream_t stream)
{
    const float* x  = (const float*)d_in[0];
    const float* cb = (const float*)d_in[1];
    float* out      = (float*)d_out;
    float* bsum     = (float*)d_ws;      // NBLK floats of scratch

    vq_main<<<NBLK, BLOCK, 0, stream>>>(x, cb, out, bsum);
    vq_final<<<1, NBLK, 0, stream>>>(bsum, out + (size_t)(32 * 64 * 64 * 64));
}

// Round 3
// 210.370 us; speedup vs baseline: 1.1753x; 1.1753x over previous
//
#include <hip/hip_runtime.h>

// VQ-VAE vector quantizer fwd, MI355X — MFMA bf16-split distance + exact rescue.
// d_in[0] = inputs f32 [32,64,64,64] (NCHW), d_in[1] = codebook f32 [512,64]
// d_out   = quantized_st f32 [32,64,64,64] ++ loss scalar.

#define NUM_EMB 512
#define DIM     64
#define HW      4096
#define NPIX    131072
#define NELEM   8388608.0f
#define MARGIN  6e-5f

typedef __attribute__((ext_vector_type(8))) short bf16x8;
typedef __attribute__((ext_vector_type(4))) float f32x4;

// ws layout (bytes); requires ws_size >= 401408
#define WS_BFRAG 0        // 131072 B : uint4[c=32][ks=2][h=2][lane=64]
#define WS_EN2   131072   // 2048 B   : f32[512] exact ||e||^2 (round-2 order)
#define WS_IDX   133120   // 262144 B : u16[NPIX] winner | 0xFFFF = unsure
#define WS_BS1   395264   // 2048 B   : f32[512] per-block loss partials (sure)
#define WS_BS2   397312   // 4096 B   : f32[1024] per-wave loss partials (fixup)

__device__ __forceinline__ unsigned short bf16_rne(float f) {
    unsigned int u = __float_as_uint(f);
    unsigned int r = u + 0x7FFFu + ((u >> 16) & 1u);
    return (unsigned short)(r >> 16);
}
__device__ __forceinline__ float bf16_to_f32(unsigned short h) {
    return __uint_as_float(((unsigned int)h) << 16);
}

// ---------------- setup: en2 + swizzled bf16-split B fragments of (-2e) -----
__global__ void vq_setup(const float* __restrict__ cb, float* __restrict__ ws)
{
    const int tid = threadIdx.x;
    const int c   = blockIdx.x;          // 32 blocks, one code-chunk each
    // en2 (block 0 only): exact, identical op order to the proven round-2 kernel
    if (c == 0) {
        float* en2s = ws + WS_EN2 / 4;
        for (int k = tid; k < NUM_EMB; k += 256) {
            const float4* row = (const float4*)(cb + k * DIM);
            float s = 0.f;
#pragma unroll
            for (int c4 = 0; c4 < DIM / 4; ++c4) {
                float4 e = row[c4];
                s += e.x * e.x + e.y * e.y + e.z * e.z + e.w * e.w;
            }
            en2s[k] = s;
        }
    }
    // B-frags: lane l slot j  <->  code = c*16 + (l&15), dim = ks*32 + (l>>4)*8 + j
    unsigned int* bf = (unsigned int*)ws;  // WS_BFRAG
    const int lane = tid & 63;
    const int quad = tid >> 6;             // ks = quad>>1, h = quad&1
    const int ks = quad >> 1, h = quad & 1;
    const int code = c * 16 + (lane & 15);
    const int dg = (lane >> 4) * 8;
    unsigned int outw[4];
#pragma unroll
    for (int j2 = 0; j2 < 4; ++j2) {
        unsigned short halves[2];
#pragma unroll
        for (int t = 0; t < 2; ++t) {
            const int j = j2 * 2 + t;
            const int dim = ks * 32 + dg + j;
            const float v = -2.0f * cb[code * DIM + dim];   // exact scaling
            const unsigned short vh = bf16_rne(v);
            const float lo = v - bf16_to_f32(vh);           // exact residual
            const unsigned short vl = bf16_rne(lo);
            halves[t] = h ? vl : vh;
        }
        outw[j2] = (unsigned int)halves[0] | ((unsigned int)halves[1] << 16);
    }
    unsigned int* dst = bf + (((c * 2 + ks) * 2 + h) * 64 + lane) * 4;
    dst[0] = outw[0]; dst[1] = outw[1]; dst[2] = outw[2]; dst[3] = outw[3];
}

// ---------------- K1: MFMA distance + top-2 + margin flag --------------------
__global__ __launch_bounds__(256, 2) void vq_mfma(
    const float* __restrict__ x, float* __restrict__ ws)
{
    const float* en2s = ws + WS_EN2 / 4;
    const uint4* bf   = (const uint4*)ws;
    unsigned short* idxb = (unsigned short*)((char*)ws + WS_IDX);

    __shared__ float en2l[NUM_EMB];
    for (int i = threadIdx.x; i < NUM_EMB; i += 256) en2l[i] = en2s[i];
    __syncthreads();

    const int l   = threadIdx.x & 63;
    const int w   = threadIdx.x >> 6;
    const int pwb = blockIdx.x * 256 + w * 64;   // wave's 64-pixel base
    const int b   = pwb >> 12;                   // image index (uniform per block)
    const int hwb = (pwb & 4095) + (l & 15);     // + t*16 later
    const int dg  = (l >> 4) * 8;
    const float* xb = x + (size_t)b * (DIM * HW);

    // A fragments: x split hi/lo, [tile][kstep]; lane row = l&15, dims dg..dg+7
    bf16x8 ah[4][2], al[4][2];
#pragma unroll
    for (int t = 0; t < 4; ++t)
#pragma unroll
        for (int ks = 0; ks < 2; ++ks)
#pragma unroll
            for (int j = 0; j < 8; ++j) {
                const int d = ks * 32 + dg + j;
                const float v = xb[(size_t)d * HW + hwb + t * 16];
                const unsigned short vh = bf16_rne(v);
                const float lo = v - bf16_to_f32(vh);
                ah[t][ks][j] = (short)vh;
                al[t][ks][j] = (short)bf16_rne(lo);
            }

    float m1[16], m2[16]; int i1[16];
#pragma unroll
    for (int s = 0; s < 16; ++s) { m1[s] = 3.4e38f; m2[s] = 3.4e38f; i1[s] = 0; }

    const int mycol = l & 15;
#define MFMA_B __builtin_amdgcn_mfma_f32_16x16x32_bf16
    for (int c = 0; c < 32; ++c) {
        const uint4 u_h0 = bf[c * 256 + 0 * 128 + 0 * 64 + l];
        const uint4 u_h1 = bf[c * 256 + 1 * 128 + 0 * 64 + l];
        const uint4 u_l0 = bf[c * 256 + 0 * 128 + 1 * 64 + l];
        const uint4 u_l1 = bf[c * 256 + 1 * 128 + 1 * 64 + l];
        const bf16x8 bh0 = __builtin_bit_cast(bf16x8, u_h0);
        const bf16x8 bh1 = __builtin_bit_cast(bf16x8, u_h1);
        const bf16x8 bl0 = __builtin_bit_cast(bf16x8, u_l0);
        const bf16x8 bl1 = __builtin_bit_cast(bf16x8, u_l1);
        const float ev = en2l[c * 16 + mycol];

        f32x4 acc[4];
#pragma unroll
        for (int t = 0; t < 4; ++t) acc[t] = (f32x4){ev, ev, ev, ev};
        // hi*hi (2 ksteps), lo*hi, hi*lo — drop lo*lo. 24 MFMA, 4 indep chains.
#pragma unroll
        for (int t = 0; t < 4; ++t) acc[t] = MFMA_B(ah[t][0], bh0, acc[t], 0, 0, 0);
#pragma unroll
        for (int t = 0; t < 4; ++t) acc[t] = MFMA_B(ah[t][1], bh1, acc[t], 0, 0, 0);
#pragma unroll
        for (int t = 0; t < 4; ++t) acc[t] = MFMA_B(al[t][0], bh0, acc[t], 0, 0, 0);
#pragma unroll
        for (int t = 0; t < 4; ++t) acc[t] = MFMA_B(al[t][1], bh1, acc[t], 0, 0, 0);
#pragma unroll
        for (int t = 0; t < 4; ++t) acc[t] = MFMA_B(ah[t][0], bl0, acc[t], 0, 0, 0);
#pragma unroll
        for (int t = 0; t < 4; ++t) acc[t] = MFMA_B(ah[t][1], bl1, acc[t], 0, 0, 0);

        // top-2 tracking; ascending c => strict < keeps first (lowest) index
#pragma unroll
        for (int t = 0; t < 4; ++t)
#pragma unroll
            for (int r = 0; r < 4; ++r) {
                const int s = t * 4 + r;
                const float v = acc[t][r];
                const bool lt = v < m1[s];
                m2[s] = fminf(m2[s], fmaxf(m1[s], v));
                i1[s] = lt ? (c * 16 + mycol) : i1[s];
                m1[s] = fminf(m1[s], v);
            }
    }

    // merge top-2 across the 16 lanes sharing each pixel row (xor bits 0-3)
#pragma unroll
    for (int s = 0; s < 16; ++s) {
        float a1 = m1[s], a2 = m2[s]; int ai = i1[s];
#pragma unroll
        for (int off = 1; off < 16; off <<= 1) {
            const float b1 = __shfl_xor(a1, off);
            const float b2 = __shfl_xor(a2, off);
            const int   bi = __shfl_xor(ai, off);
            a2 = fminf(fminf(a2, b2), fmaxf(a1, b1));
            const bool take = (b1 < a1) || ((b1 == a1) && (bi < ai));
            ai = take ? bi : ai;
            a1 = fminf(a1, b1);
        }
        m1[s] = a1; m2[s] = a2; i1[s] = ai;
    }

    // writer: lane (l&15)==0 of each group g writes rows g*4+r for all tiles
    if ((l & 15) == 0) {
        const int g = l >> 4;
#pragma unroll
        for (int t = 0; t < 4; ++t)
#pragma unroll
            for (int r = 0; r < 4; ++r) {
                const int s = t * 4 + r;
                const int p = pwb + t * 16 + g * 4 + r;
                const unsigned short v =
                    ((m2[s] - m1[s]) > MARGIN) ? (unsigned short)i1[s]
                                               : (unsigned short)0xFFFF;
                idxb[p] = v;
            }
    }
}

// ---------------- K2: gather + ST output + loss partials (sure pixels) ------
__global__ __launch_bounds__(256, 2) void vq_epilogue(
    const float* __restrict__ x, const float* __restrict__ cb,
    float* __restrict__ out, float* __restrict__ ws)
{
    const unsigned short* idxb = (const unsigned short*)((const char*)ws + WS_IDX);
    float* bs1 = ws + WS_BS1 / 4;
    __shared__ float wsum[4];

    const int p  = blockIdx.x * 256 + threadIdx.x;
    const int b  = p >> 12;
    const int hw = p & 4095;
    const float* xp = x + (size_t)b * (DIM * HW) + hw;
    float* op       = out + (size_t)b * (DIM * HW) + hw;

    const unsigned short f = idxb[p];
    float lsum = 0.f;
    if (f != (unsigned short)0xFFFF) {
        const float4* qrow = (const float4*)(cb + (int)f * DIM);
#pragma unroll
        for (int c4 = 0; c4 < DIM / 4; ++c4) {
            const float4 e = qrow[c4];
            const float x0 = xp[(size_t)(4 * c4 + 0) * HW];
            const float x1 = xp[(size_t)(4 * c4 + 1) * HW];
            const float x2 = xp[(size_t)(4 * c4 + 2) * HW];
            const float x3 = xp[(size_t)(4 * c4 + 3) * HW];
            const float dx0 = e.x - x0, dx1 = e.y - x1;
            const float dx2 = e.z - x2, dx3 = e.w - x3;
            op[(size_t)(4 * c4 + 0) * HW] = x0 + dx0;   // x + (q-x), ref ST rounding
            op[(size_t)(4 * c4 + 1) * HW] = x1 + dx1;
            op[(size_t)(4 * c4 + 2) * HW] = x2 + dx2;
            op[(size_t)(4 * c4 + 3) * HW] = x3 + dx3;
            lsum = fmaf(dx0, dx0, lsum);
            lsum = fmaf(dx1, dx1, lsum);
            lsum = fmaf(dx2, dx2, lsum);
            lsum = fmaf(dx3, dx3, lsum);
        }
    }
#pragma unroll
    for (int off = 32; off > 0; off >>= 1)
        lsum += __shfl_xor(lsum, off);
    const int wid = threadIdx.x >> 6;
    if ((threadIdx.x & 63) == 0) wsum[wid] = lsum;
    __syncthreads();
    if (threadIdx.x == 0)
        bs1[blockIdx.x] = (wsum[0] + wsum[1]) + (wsum[2] + wsum[3]);
}

// ---------------- K3: wave-cooperative exact rescore of flagged pixels ------
__global__ void vq_fixup(
    const float* __restrict__ x, const float* __restrict__ cb,
    float* __restrict__ out, float* __restrict__ ws)
{
    const float* en2s = ws + WS_EN2 / 4;
    const unsigned short* idxb = (const unsigned short*)((const char*)ws + WS_IDX);
    float* bs2 = ws + WS_BS2 / 4;

    const int l  = threadIdx.x & 63;
    const int gw = (blockIdx.x * 256 + threadIdx.x) >> 6;   // 0..1023
    float wacc = 0.f;

    for (int slot = gw; slot < NPIX / 64; slot += 1024) {
        const unsigned short f = idxb[slot * 64 + l];
        unsigned long long mask = __ballot(f == (unsigned short)0xFFFF);
        while (mask) {
            const int u = __ffsll(mask) - 1;
            mask &= mask - 1;
            const int p  = slot * 64 + u;
            const int b  = p >> 12;
            const int hw = p & 4095;
            const float xv = x[(size_t)b * (DIM * HW) + (size_t)l * HW + hw]; // dim=l
            // xsq: sequential fma chain (round-2 order)
            float xsq = 0.f;
            for (int c = 0; c < DIM; ++c) {
                const float xc = __shfl(xv, c);
                xsq = fmaf(xc, xc, xsq);
            }
            // lane handles codes l*8 .. l*8+7; 4-chain dots, round-2 op order
            float ch0[8], ch1[8], ch2[8], ch3[8];
#pragma unroll
            for (int s = 0; s < 8; ++s) { ch0[s] = ch1[s] = ch2[s] = ch3[s] = 0.f; }
            for (int c4 = 0; c4 < DIM / 4; ++c4) {
                const float x0 = __shfl(xv, 4 * c4 + 0);
                const float x1 = __shfl(xv, 4 * c4 + 1);
                const float x2 = __shfl(xv, 4 * c4 + 2);
                const float x3 = __shfl(xv, 4 * c4 + 3);
#pragma unroll
                for (int s = 0; s < 8; ++s) {
                    const float4 e = *(const float4*)(cb + (l * 8 + s) * DIM + 4 * c4);
                    ch0[s] = fmaf(x0, e.x, ch0[s]);
                    ch1[s] = fmaf(x1, e.y, ch1[s]);
                    ch2[s] = fmaf(x2, e.z, ch2[s]);
                    ch3[s] = fmaf(x3, e.w, ch3[s]);
                }
            }
            float best = 3.4e38f; int bidx = 0;
#pragma unroll
            for (int s = 0; s < 8; ++s) {
                const float dot = (ch0[s] + ch1[s]) + (ch2[s] + ch3[s]);
                const float dist = fmaf(-2.f, dot, xsq) + en2s[l * 8 + s];
                if (dist < best) { best = dist; bidx = l * 8 + s; }
            }
#pragma unroll
            for (int off = 1; off < 64; off <<= 1) {
                const float bv = __shfl_xor(best, off);
                const int   bi = __shfl_xor(bidx, off);
                const bool take = (bv < best) || ((bv == best) && (bi < bidx));
                bidx = take ? bi : bidx;
                best = fminf(best, bv);
            }
            // write ST output + loss, lane = dim
            const float q  = cb[bidx * DIM + l];
            const float dx = q - xv;
            out[(size_t)b * (DIM * HW) + (size_t)l * HW + hw] = xv + dx;
            float c2 = dx * dx;
#pragma unroll
            for (int off = 1; off < 64; off <<= 1) c2 += __shfl_xor(c2, off);
            wacc += c2;  // identical in all lanes
        }
    }
    if (l == 0) bs2[gw] = wacc;   // written every call (0 if none flagged)
}

// ---------------- K4: final loss (bs1 tree identical to round-2) ------------
__global__ void vq_final(float* __restrict__ ws, float* __restrict__ lossp)
{
    const float* bs1 = ws + WS_BS1 / 4;
    const float* bs2 = ws + WS_BS2 / 4;
    const int t = threadIdx.x;   // 512
    __shared__ float w1[8], w2[8];
    float v1 = bs1[t];
    float v2 = bs2[t] + bs2[t + 512];
#pragma unroll
    for (int off = 32; off > 0; off >>= 1) {
        v1 += __shfl_xor(v1, off);
        v2 += __shfl_xor(v2, off);
    }
    const int wid = t >> 6;
    if ((t & 63) == 0) { w1[wid] = v1; w2[wid] = v2; }
    __syncthreads();
    if (t == 0) {
        float s1 = 0.f, s2 = 0.f;
#pragma unroll
        for (int i = 0; i < 8; ++i) s1 += w1[i];
#pragma unroll
        for (int i = 0; i < 8; ++i) s2 += w2[i];
        const float L = (s1 + s2) / NELEM;   // s2==0.0 exactly when none flagged
        *lossp = L + 0.25f * L;
    }
}

extern "C" void kernel_launch(void* const* d_in, const int* in_sizes, int n_in,
                              void* d_out, int out_size, void* d_ws, size_t ws_size,
                              hipStream_t stream)
{
    const float* x  = (const float*)d_in[0];
    const float* cb = (const float*)d_in[1];
    float* out      = (float*)d_out;
    float* wsf      = (float*)d_ws;   // needs >= 401408 bytes

    vq_setup   <<<32,  256, 0, stream>>>(cb, wsf);
    vq_mfma    <<<512, 256, 0, stream>>>(x, wsf);
    vq_epilogue<<<512, 256, 0, stream>>>(x, cb, out, wsf);
    vq_fixup   <<<256, 256, 0, stream>>>(x, cb, out, wsf);
    vq_final   <<<1,   512, 0, stream>>>(wsf, out + (size_t)NPIX * DIM);
}

// Round 6
// 181.751 us; speedup vs baseline: 1.3604x; 1.1575x over previous
//
#include <hip/hip_runtime.h>

// VQ-VAE vector quantizer fwd, MI355X — MFMA bf16-split distance + exact rescue.
// d_in[0] = inputs f32 [32,64,64,64] (NCHW), d_in[1] = codebook f32 [512,64]
// d_out   = quantized_st f32 [32,64,64,64] ++ loss scalar.
//
// Pipeline: setup (B-frags, en2, zero counter) -> mfma (dist + top2 + flag,
// append unsure pixels to worklist) -> fixup (1 wave per unsure pixel, exact
// f32 rescore, resolve idx) -> epilogue (ALL pixels: gather, ST out, loss
// partials, round-2-identical summation) -> final (loss).

#define NUM_EMB 512
#define DIM     64
#define HW      4096
#define NPIX    131072
#define NELEM   8388608.0f
#define MARGIN  6e-5f
#define LIST_CAP 65536

typedef __attribute__((ext_vector_type(8))) short bf16x8;
typedef __attribute__((ext_vector_type(4))) float f32x4;

// ws layout (bytes); requires ws_size >= 659472
#define WS_BFRAG 0        // 131072 B : uint4[c=32][ks=2][h=2][lane=64]
#define WS_EN2   131072   // 2048 B   : f32[512] exact ||e||^2 (round-2 order)
#define WS_IDX   133120   // 262144 B : u16[NPIX] winner (0xFFFF until fixup)
#define WS_BS1   395264   // 2048 B   : f32[512] per-block loss partials
#define WS_CNT   397312   // 16 B     : u32 worklist counter
#define WS_LIST  397328   // 262144 B : u32[LIST_CAP] flagged pixel ids

__device__ __forceinline__ unsigned short bf16_rne(float f) {
    unsigned int u = __float_as_uint(f);
    unsigned int r = u + 0x7FFFu + ((u >> 16) & 1u);
    return (unsigned short)(r >> 16);
}
__device__ __forceinline__ float bf16_to_f32(unsigned short h) {
    return __uint_as_float(((unsigned int)h) << 16);
}

// ---------------- setup: en2 + swizzled bf16-split B fragments of (-2e) -----
__global__ void vq_setup(const float* __restrict__ cb, float* __restrict__ ws)
{
    const int tid = threadIdx.x;
    const int c   = blockIdx.x;          // 32 blocks, one code-chunk each
    if (c == 0 && tid == 0) *(unsigned int*)((char*)ws + WS_CNT) = 0u;
    // en2 (block 0 only): exact, identical op order to the proven round-2 kernel
    if (c == 0) {
        float* en2s = ws + WS_EN2 / 4;
        for (int k = tid; k < NUM_EMB; k += 256) {
            const float4* row = (const float4*)(cb + k * DIM);
            float s = 0.f;
#pragma unroll
            for (int c4 = 0; c4 < DIM / 4; ++c4) {
                float4 e = row[c4];
                s += e.x * e.x + e.y * e.y + e.z * e.z + e.w * e.w;
            }
            en2s[k] = s;
        }
    }
    // B-frags: lane l slot j  <->  code = c*16 + (l&15), dim = ks*32 + (l>>4)*8 + j
    unsigned int* bf = (unsigned int*)ws;  // WS_BFRAG
    const int lane = tid & 63;
    const int quad = tid >> 6;             // ks = quad>>1, h = quad&1
    const int ks = quad >> 1, h = quad & 1;
    const int code = c * 16 + (lane & 15);
    const int dg = (lane >> 4) * 8;
    unsigned int outw[4];
#pragma unroll
    for (int j2 = 0; j2 < 4; ++j2) {
        unsigned short halves[2];
#pragma unroll
        for (int t = 0; t < 2; ++t) {
            const int j = j2 * 2 + t;
            const int dim = ks * 32 + dg + j;
            const float v = -2.0f * cb[code * DIM + dim];   // exact scaling
            const unsigned short vh = bf16_rne(v);
            const float lo = v - bf16_to_f32(vh);           // exact residual
            const unsigned short vl = bf16_rne(lo);
            halves[t] = h ? vl : vh;
        }
        outw[j2] = (unsigned int)halves[0] | ((unsigned int)halves[1] << 16);
    }
    unsigned int* dst = bf + (((c * 2 + ks) * 2 + h) * 64 + lane) * 4;
    dst[0] = outw[0]; dst[1] = outw[1]; dst[2] = outw[2]; dst[3] = outw[3];
}

// ---------------- K1: MFMA distance + top-2 + margin flag --------------------
__global__ __launch_bounds__(256, 2) void vq_mfma(
    const float* __restrict__ x, float* __restrict__ ws)
{
    const float* en2s = ws + WS_EN2 / 4;
    const uint4* bf   = (const uint4*)ws;
    unsigned short* idxb = (unsigned short*)((char*)ws + WS_IDX);
    unsigned int* cntp = (unsigned int*)((char*)ws + WS_CNT);
    unsigned int* list = (unsigned int*)((char*)ws + WS_LIST);

    __shared__ float en2l[NUM_EMB];
    for (int i = threadIdx.x; i < NUM_EMB; i += 256) en2l[i] = en2s[i];
    __syncthreads();

    const int l   = threadIdx.x & 63;
    const int w   = threadIdx.x >> 6;
    const int pwb = blockIdx.x * 256 + w * 64;   // wave's 64-pixel base
    const int b   = pwb >> 12;                   // image index (uniform per block)
    const int hwb = (pwb & 4095) + (l & 15);     // + t*16 later
    const int dg  = (l >> 4) * 8;
    const float* xb = x + (size_t)b * (DIM * HW);

    // A fragments: x split hi/lo, [tile][kstep]; lane row = l&15, dims dg..dg+7
    bf16x8 ah[4][2], al[4][2];
#pragma unroll
    for (int t = 0; t < 4; ++t)
#pragma unroll
        for (int ks = 0; ks < 2; ++ks)
#pragma unroll
            for (int j = 0; j < 8; ++j) {
                const int d = ks * 32 + dg + j;
                const float v = xb[(size_t)d * HW + hwb + t * 16];
                const unsigned short vh = bf16_rne(v);
                const float lo = v - bf16_to_f32(vh);
                ah[t][ks][j] = (short)vh;
                al[t][ks][j] = (short)bf16_rne(lo);
            }

    float m1[16], m2[16]; int i1[16];
#pragma unroll
    for (int s = 0; s < 16; ++s) { m1[s] = 3.4e38f; m2[s] = 3.4e38f; i1[s] = 0; }

    const int mycol = l & 15;
#define MFMA_B __builtin_amdgcn_mfma_f32_16x16x32_bf16
    for (int c = 0; c < 32; ++c) {
        const uint4 u_h0 = bf[c * 256 + 0 * 128 + 0 * 64 + l];
        const uint4 u_h1 = bf[c * 256 + 1 * 128 + 0 * 64 + l];
        const uint4 u_l0 = bf[c * 256 + 0 * 128 + 1 * 64 + l];
        const uint4 u_l1 = bf[c * 256 + 1 * 128 + 1 * 64 + l];
        const bf16x8 bh0 = __builtin_bit_cast(bf16x8, u_h0);
        const bf16x8 bh1 = __builtin_bit_cast(bf16x8, u_h1);
        const bf16x8 bl0 = __builtin_bit_cast(bf16x8, u_l0);
        const bf16x8 bl1 = __builtin_bit_cast(bf16x8, u_l1);
        const float ev = en2l[c * 16 + mycol];

        f32x4 acc[4];
#pragma unroll
        for (int t = 0; t < 4; ++t) acc[t] = (f32x4){ev, ev, ev, ev};
        // hi*hi (2 ksteps), lo*hi, hi*lo — drop lo*lo. 24 MFMA, 4 indep chains.
#pragma unroll
        for (int t = 0; t < 4; ++t) acc[t] = MFMA_B(ah[t][0], bh0, acc[t], 0, 0, 0);
#pragma unroll
        for (int t = 0; t < 4; ++t) acc[t] = MFMA_B(ah[t][1], bh1, acc[t], 0, 0, 0);
#pragma unroll
        for (int t = 0; t < 4; ++t) acc[t] = MFMA_B(al[t][0], bh0, acc[t], 0, 0, 0);
#pragma unroll
        for (int t = 0; t < 4; ++t) acc[t] = MFMA_B(al[t][1], bh1, acc[t], 0, 0, 0);
#pragma unroll
        for (int t = 0; t < 4; ++t) acc[t] = MFMA_B(ah[t][0], bl0, acc[t], 0, 0, 0);
#pragma unroll
        for (int t = 0; t < 4; ++t) acc[t] = MFMA_B(ah[t][1], bl1, acc[t], 0, 0, 0);

        // top-2 tracking; ascending c => strict < keeps first (lowest) index
#pragma unroll
        for (int t = 0; t < 4; ++t)
#pragma unroll
            for (int r = 0; r < 4; ++r) {
                const int s = t * 4 + r;
                const float v = acc[t][r];
                const bool lt = v < m1[s];
                m2[s] = fminf(m2[s], fmaxf(m1[s], v));
                i1[s] = lt ? (c * 16 + mycol) : i1[s];
                m1[s] = fminf(m1[s], v);
            }
    }

    // merge top-2 across the 16 lanes sharing each pixel row (xor bits 0-3)
#pragma unroll
    for (int s = 0; s < 16; ++s) {
        float a1 = m1[s], a2 = m2[s]; int ai = i1[s];
#pragma unroll
        for (int off = 1; off < 16; off <<= 1) {
            const float b1 = __shfl_xor(a1, off);
            const float b2 = __shfl_xor(a2, off);
            const int   bi = __shfl_xor(ai, off);
            a2 = fminf(fminf(a2, b2), fmaxf(a1, b1));
            const bool take = (b1 < a1) || ((b1 == a1) && (bi < ai));
            ai = take ? bi : ai;
            a1 = fminf(a1, b1);
        }
        m1[s] = a1; m2[s] = a2; i1[s] = ai;
    }

    // writer: lane (l&15)==0 of each group g writes rows g*4+r for all tiles.
    // Unsure pixels -> worklist (order nondeterministic, results are not).
    if ((l & 15) == 0) {
        const int g = l >> 4;
#pragma unroll
        for (int t = 0; t < 4; ++t)
#pragma unroll
            for (int r = 0; r < 4; ++r) {
                const int s = t * 4 + r;
                const int p = pwb + t * 16 + g * 4 + r;
                unsigned short v = (unsigned short)i1[s];
                if ((m2[s] - m1[s]) <= MARGIN) {
                    const unsigned int slot = atomicAdd(cntp, 1u);
                    if (slot < LIST_CAP) { list[slot] = (unsigned int)p; v = 0xFFFFu; }
                    // overflow (can't happen at ~1% flag rate): keep approx winner
                }
                idxb[p] = v;
            }
    }
}

// ---------------- K2: exact rescore, ONE flagged pixel per wave --------------
__global__ __launch_bounds__(64) void vq_fixup(
    const float* __restrict__ x, const float* __restrict__ cb,
    float* __restrict__ ws)
{
    const float* en2s = ws + WS_EN2 / 4;
    unsigned short* idxb = (unsigned short*)((char*)ws + WS_IDX);
    const unsigned int* list = (const unsigned int*)((const char*)ws + WS_LIST);
    unsigned int cnt = *(const unsigned int*)((const char*)ws + WS_CNT);
    if (cnt > LIST_CAP) cnt = LIST_CAP;

    const int l = threadIdx.x;           // block = 1 wave
    for (unsigned int wi = blockIdx.x; wi < cnt; wi += gridDim.x) {
        const int p  = (int)list[wi];
        const int b  = p >> 12;
        const int hw = p & 4095;
        const float xv = x[(size_t)b * (DIM * HW) + (size_t)l * HW + hw]; // dim=l
        // xsq: sequential fma chain (round-2 order)
        float xsq = 0.f;
        for (int c = 0; c < DIM; ++c) {
            const float xc = __shfl(xv, c);
            xsq = fmaf(xc, xc, xsq);
        }
        // lane handles codes l*8 .. l*8+7; 4-chain dots, round-2 op order
        float ch0[8], ch1[8], ch2[8], ch3[8];
#pragma unroll
        for (int s = 0; s < 8; ++s) { ch0[s] = ch1[s] = ch2[s] = ch3[s] = 0.f; }
        for (int c4 = 0; c4 < DIM / 4; ++c4) {
            const float x0 = __shfl(xv, 4 * c4 + 0);
            const float x1 = __shfl(xv, 4 * c4 + 1);
            const float x2 = __shfl(xv, 4 * c4 + 2);
            const float x3 = __shfl(xv, 4 * c4 + 3);
#pragma unroll
            for (int s = 0; s < 8; ++s) {
                const float4 e = *(const float4*)(cb + (l * 8 + s) * DIM + 4 * c4);
                ch0[s] = fmaf(x0, e.x, ch0[s]);
                ch1[s] = fmaf(x1, e.y, ch1[s]);
                ch2[s] = fmaf(x2, e.z, ch2[s]);
                ch3[s] = fmaf(x3, e.w, ch3[s]);
            }
        }
        float best = 3.4e38f; int bidx = 0;
#pragma unroll
        for (int s = 0; s < 8; ++s) {
            const float dot = (ch0[s] + ch1[s]) + (ch2[s] + ch3[s]);
            const float dist = fmaf(-2.f, dot, xsq) + en2s[l * 8 + s];
            if (dist < best) { best = dist; bidx = l * 8 + s; }
        }
#pragma unroll
        for (int off = 1; off < 64; off <<= 1) {
            const float bv = __shfl_xor(best, off);
            const int   bi = __shfl_xor(bidx, off);
            const bool take = (bv < best) || ((bv == best) && (bi < bidx));
            bidx = take ? bi : bidx;
            best = fminf(best, bv);
        }
        if (l == 0) idxb[p] = (unsigned short)bidx;   // resolve index only
    }
}

// ---------------- K3: gather + ST output + loss partials (ALL pixels) -------
__global__ __launch_bounds__(256, 2) void vq_epilogue(
    const float* __restrict__ x, const float* __restrict__ cb,
    float* __restrict__ out, float* __restrict__ ws)
{
    const unsigned short* idxb = (const unsigned short*)((const char*)ws + WS_IDX);
    float* bs1 = ws + WS_BS1 / 4;
    __shared__ float wsum[4];

    const int p  = blockIdx.x * 256 + threadIdx.x;
    const int b  = p >> 12;
    const int hw = p & 4095;
    const float* xp = x + (size_t)b * (DIM * HW) + hw;
    float* op       = out + (size_t)b * (DIM * HW) + hw;

    const int f = (int)idxb[p];          // always a valid code after fixup
    const float4* qrow = (const float4*)(cb + f * DIM);
    float lsum = 0.f;
#pragma unroll
    for (int c4 = 0; c4 < DIM / 4; ++c4) {
        const float4 e = qrow[c4];
        const float x0 = xp[(size_t)(4 * c4 + 0) * HW];
        const float x1 = xp[(size_t)(4 * c4 + 1) * HW];
        const float x2 = xp[(size_t)(4 * c4 + 2) * HW];
        const float x3 = xp[(size_t)(4 * c4 + 3) * HW];
        const float dx0 = e.x - x0, dx1 = e.y - x1;
        const float dx2 = e.z - x2, dx3 = e.w - x3;
        op[(size_t)(4 * c4 + 0) * HW] = x0 + dx0;   // x + (q-x), ref ST rounding
        op[(size_t)(4 * c4 + 1) * HW] = x1 + dx1;
        op[(size_t)(4 * c4 + 2) * HW] = x2 + dx2;
        op[(size_t)(4 * c4 + 3) * HW] = x3 + dx3;
        lsum = fmaf(dx0, dx0, lsum);
        lsum = fmaf(dx1, dx1, lsum);
        lsum = fmaf(dx2, dx2, lsum);
        lsum = fmaf(dx3, dx3, lsum);
    }
#pragma unroll
    for (int off = 32; off > 0; off >>= 1)
        lsum += __shfl_xor(lsum, off);
    const int wid = threadIdx.x >> 6;
    if ((threadIdx.x & 63) == 0) wsum[wid] = lsum;
    __syncthreads();
    if (threadIdx.x == 0)
        bs1[blockIdx.x] = (wsum[0] + wsum[1]) + (wsum[2] + wsum[3]);
}

// ---------------- K4: final loss (identical tree to round-2) ----------------
__global__ void vq_final(float* __restrict__ ws, float* __restrict__ lossp)
{
    const float* bs1 = ws + WS_BS1 / 4;
    float v = bs1[threadIdx.x];          // 512 threads, one partial each
#pragma unroll
    for (int off = 32; off > 0; off >>= 1)
        v += __shfl_xor(v, off);
    __shared__ float wsh[8];
    const int wid = threadIdx.x >> 6;
    if ((threadIdx.x & 63) == 0) wsh[wid] = v;
    __syncthreads();
    if (threadIdx.x == 0) {
        float s = 0.f;
#pragma unroll
        for (int i = 0; i < 8; ++i) s += wsh[i];
        const float L = s / NELEM;       // mean squared error (== both loss terms)
        *lossp = L + 0.25f * L;          // q_latent + commitment*e_latent
    }
}

extern "C" void kernel_launch(void* const* d_in, const int* in_sizes, int n_in,
                              void* d_out, int out_size, void* d_ws, size_t ws_size,
                              hipStream_t stream)
{
    const float* x  = (const float*)d_in[0];
    const float* cb = (const float*)d_in[1];
    float* out      = (float*)d_out;
    float* wsf      = (float*)d_ws;   // needs >= 659472 bytes

    vq_setup   <<<32,   256, 0, stream>>>(cb, wsf);
    vq_mfma    <<<512,  256, 0, stream>>>(x, wsf);
    vq_fixup   <<<2048,  64, 0, stream>>>(x, cb, wsf);
    vq_epilogue<<<512,  256, 0, stream>>>(x, cb, out, wsf);
    vq_final   <<<1,    512, 0, stream>>>(wsf, out + (size_t)NPIX * DIM);
}

// Round 8
// 172.401 us; speedup vs baseline: 1.4342x; 1.0542x over previous
//
#include <hip/hip_runtime.h>

// VQ-VAE vector quantizer fwd, MI355X — MFMA bf16-split distance + exact rescue.
// d_in[0] = inputs f32 [32,64,64,64] (NCHW), d_in[1] = codebook f32 [512,64]
// d_out   = quantized_st f32 [32,64,64,64] ++ loss scalar.
//
// Pipeline: setup (B-frags, en2, zero counter) -> mfma (dist + top2 + flag,
// append unsure pixels to worklist) -> fixup (1 wave per unsure pixel, exact
// f32 rescore, resolve idx) -> epilogue (ALL pixels: gather, ST out, loss
// partials, round-2-identical summation) -> final (loss).
//
// R6: vq_mfma was latency-bound (54us, occ 17%, MfmaUtil 18%, VALUBusy 37%).
// R7: 2 tiles/wave (grid 1024, 4 blocks/CU) + register double-buffered B-frag
// prefetch. Per-pixel arithmetic unchanged => outputs/loss bit-identical.

#define NUM_EMB 512
#define DIM     64
#define HW      4096
#define NPIX    131072
#define NELEM   8388608.0f
#define MARGIN  6e-5f
#define LIST_CAP 65536

typedef __attribute__((ext_vector_type(8))) short bf16x8;
typedef __attribute__((ext_vector_type(4))) float f32x4;

// ws layout (bytes); requires ws_size >= 659472
#define WS_BFRAG 0        // 131072 B : uint4[c=32][ks=2][h=2][lane=64]
#define WS_EN2   131072   // 2048 B   : f32[512] exact ||e||^2 (round-2 order)
#define WS_IDX   133120   // 262144 B : u16[NPIX] winner (0xFFFF until fixup)
#define WS_BS1   395264   // 2048 B   : f32[512] per-block loss partials
#define WS_CNT   397312   // 16 B     : u32 worklist counter
#define WS_LIST  397328   // 262144 B : u32[LIST_CAP] flagged pixel ids

__device__ __forceinline__ unsigned short bf16_rne(float f) {
    unsigned int u = __float_as_uint(f);
    unsigned int r = u + 0x7FFFu + ((u >> 16) & 1u);
    return (unsigned short)(r >> 16);
}
__device__ __forceinline__ float bf16_to_f32(unsigned short h) {
    return __uint_as_float(((unsigned int)h) << 16);
}

// ---------------- setup: en2 + swizzled bf16-split B fragments of (-2e) -----
__global__ void vq_setup(const float* __restrict__ cb, float* __restrict__ ws)
{
    const int tid = threadIdx.x;
    const int c   = blockIdx.x;          // 32 blocks, one code-chunk each
    if (c == 0 && tid == 0) *(unsigned int*)((char*)ws + WS_CNT) = 0u;
    // en2 (block 0 only): exact, identical op order to the proven round-2 kernel
    if (c == 0) {
        float* en2s = ws + WS_EN2 / 4;
        for (int k = tid; k < NUM_EMB; k += 256) {
            const float4* row = (const float4*)(cb + k * DIM);
            float s = 0.f;
#pragma unroll
            for (int c4 = 0; c4 < DIM / 4; ++c4) {
                float4 e = row[c4];
                s += e.x * e.x + e.y * e.y + e.z * e.z + e.w * e.w;
            }
            en2s[k] = s;
        }
    }
    // B-frags: lane l slot j  <->  code = c*16 + (l&15), dim = ks*32 + (l>>4)*8 + j
    unsigned int* bf = (unsigned int*)ws;  // WS_BFRAG
    const int lane = tid & 63;
    const int quad = tid >> 6;             // ks = quad>>1, h = quad&1
    const int ks = quad >> 1, h = quad & 1;
    const int code = c * 16 + (lane & 15);
    const int dg = (lane >> 4) * 8;
    unsigned int outw[4];
#pragma unroll
    for (int j2 = 0; j2 < 4; ++j2) {
        unsigned short halves[2];
#pragma unroll
        for (int t = 0; t < 2; ++t) {
            const int j = j2 * 2 + t;
            const int dim = ks * 32 + dg + j;
            const float v = -2.0f * cb[code * DIM + dim];   // exact scaling
            const unsigned short vh = bf16_rne(v);
            const float lo = v - bf16_to_f32(vh);           // exact residual
            const unsigned short vl = bf16_rne(lo);
            halves[t] = h ? vl : vh;
        }
        outw[j2] = (unsigned int)halves[0] | ((unsigned int)halves[1] << 16);
    }
    unsigned int* dst = bf + (((c * 2 + ks) * 2 + h) * 64 + lane) * 4;
    dst[0] = outw[0]; dst[1] = outw[1]; dst[2] = outw[2]; dst[3] = outw[3];
}

// ---------------- K1: MFMA distance + top-2 + margin flag --------------------
// 2 tiles (32 pixels) per wave, grid 1024 => 4 blocks/CU. B-frags prefetched
// one c-iteration ahead in registers.
__global__ __launch_bounds__(256, 4) void vq_mfma(
    const float* __restrict__ x, float* __restrict__ ws)
{
    const float* en2s = ws + WS_EN2 / 4;
    const uint4* bf   = (const uint4*)ws;
    unsigned short* idxb = (unsigned short*)((char*)ws + WS_IDX);
    unsigned int* cntp = (unsigned int*)((char*)ws + WS_CNT);
    unsigned int* list = (unsigned int*)((char*)ws + WS_LIST);

    __shared__ float en2l[NUM_EMB];
    for (int i = threadIdx.x; i < NUM_EMB; i += 256) en2l[i] = en2s[i];
    __syncthreads();

    const int l   = threadIdx.x & 63;
    const int w   = threadIdx.x >> 6;
    const int pwb = blockIdx.x * 128 + w * 32;   // wave's 32-pixel base
    const int b   = pwb >> 12;                   // image index (uniform per block)
    const int hwb = (pwb & 4095) + (l & 15);     // + t*16 later
    const int dg  = (l >> 4) * 8;
    const float* xb = x + (size_t)b * (DIM * HW);

    // A fragments: x split hi/lo, [tile][kstep]; lane row = l&15, dims dg..dg+7
    bf16x8 ah[2][2], al[2][2];
#pragma unroll
    for (int t = 0; t < 2; ++t)
#pragma unroll
        for (int ks = 0; ks < 2; ++ks)
#pragma unroll
            for (int j = 0; j < 8; ++j) {
                const int d = ks * 32 + dg + j;
                const float v = xb[(size_t)d * HW + hwb + t * 16];
                const unsigned short vh = bf16_rne(v);
                const float lo = v - bf16_to_f32(vh);
                ah[t][ks][j] = (short)vh;
                al[t][ks][j] = (short)bf16_rne(lo);
            }

    float m1[8], m2[8]; int i1[8];
#pragma unroll
    for (int s = 0; s < 8; ++s) { m1[s] = 3.4e38f; m2[s] = 3.4e38f; i1[s] = 0; }

    const int mycol = l & 15;
#define MFMA_B __builtin_amdgcn_mfma_f32_16x16x32_bf16

    // register double-buffer of the 4 B-frag uint4 per c-iteration
    uint4 cb0, cb1, cb2, cb3;   // current: h0(ks0), h1(ks1), l0(ks0), l1(ks1)
    cb0 = bf[0 * 256 + 0 * 128 + 0 * 64 + l];
    cb1 = bf[0 * 256 + 1 * 128 + 0 * 64 + l];
    cb2 = bf[0 * 256 + 0 * 128 + 1 * 64 + l];
    cb3 = bf[0 * 256 + 1 * 128 + 1 * 64 + l];

    for (int c = 0; c < 32; ++c) {
        // prefetch next c's B-frags before touching this c's (hide L2 latency)
        uint4 nb0, nb1, nb2, nb3;
        if (c < 31) {
            nb0 = bf[(c + 1) * 256 + 0 * 128 + 0 * 64 + l];
            nb1 = bf[(c + 1) * 256 + 1 * 128 + 0 * 64 + l];
            nb2 = bf[(c + 1) * 256 + 0 * 128 + 1 * 64 + l];
            nb3 = bf[(c + 1) * 256 + 1 * 128 + 1 * 64 + l];
        }
        const bf16x8 bh0 = __builtin_bit_cast(bf16x8, cb0);
        const bf16x8 bh1 = __builtin_bit_cast(bf16x8, cb1);
        const bf16x8 bl0 = __builtin_bit_cast(bf16x8, cb2);
        const bf16x8 bl1 = __builtin_bit_cast(bf16x8, cb3);
        const float ev = en2l[c * 16 + mycol];

        f32x4 acc[2];
#pragma unroll
        for (int t = 0; t < 2; ++t) acc[t] = (f32x4){ev, ev, ev, ev};
        // hi*hi (2 ksteps), lo*hi, hi*lo — drop lo*lo. Same per-tile chain
        // order as round-2/3 (bit-identical distances).
#pragma unroll
        for (int t = 0; t < 2; ++t) acc[t] = MFMA_B(ah[t][0], bh0, acc[t], 0, 0, 0);
#pragma unroll
        for (int t = 0; t < 2; ++t) acc[t] = MFMA_B(ah[t][1], bh1, acc[t], 0, 0, 0);
#pragma unroll
        for (int t = 0; t < 2; ++t) acc[t] = MFMA_B(al[t][0], bh0, acc[t], 0, 0, 0);
#pragma unroll
        for (int t = 0; t < 2; ++t) acc[t] = MFMA_B(al[t][1], bh1, acc[t], 0, 0, 0);
#pragma unroll
        for (int t = 0; t < 2; ++t) acc[t] = MFMA_B(ah[t][0], bl0, acc[t], 0, 0, 0);
#pragma unroll
        for (int t = 0; t < 2; ++t) acc[t] = MFMA_B(ah[t][1], bl1, acc[t], 0, 0, 0);

        // top-2 tracking; ascending c => strict < keeps first (lowest) index
#pragma unroll
        for (int t = 0; t < 2; ++t)
#pragma unroll
            for (int r = 0; r < 4; ++r) {
                const int s = t * 4 + r;
                const float v = acc[t][r];
                const bool lt = v < m1[s];
                m2[s] = fminf(m2[s], fmaxf(m1[s], v));
                i1[s] = lt ? (c * 16 + mycol) : i1[s];
                m1[s] = fminf(m1[s], v);
            }
        cb0 = nb0; cb1 = nb1; cb2 = nb2; cb3 = nb3;
    }

    // merge top-2 across the 16 lanes sharing each pixel row (xor bits 0-3)
#pragma unroll
    for (int s = 0; s < 8; ++s) {
        float a1 = m1[s], a2 = m2[s]; int ai = i1[s];
#pragma unroll
        for (int off = 1; off < 16; off <<= 1) {
            const float b1 = __shfl_xor(a1, off);
            const float b2 = __shfl_xor(a2, off);
            const int   bi = __shfl_xor(ai, off);
            a2 = fminf(fminf(a2, b2), fmaxf(a1, b1));
            const bool take = (b1 < a1) || ((b1 == a1) && (bi < ai));
            ai = take ? bi : ai;
            a1 = fminf(a1, b1);
        }
        m1[s] = a1; m2[s] = a2; i1[s] = ai;
    }

    // writer: lane (l&15)==0 of each group g writes rows g*4+r for both tiles.
    // Unsure pixels -> worklist (order nondeterministic, results are not).
    if ((l & 15) == 0) {
        const int g = l >> 4;
#pragma unroll
        for (int t = 0; t < 2; ++t)
#pragma unroll
            for (int r = 0; r < 4; ++r) {
                const int s = t * 4 + r;
                const int p = pwb + t * 16 + g * 4 + r;
                unsigned short v = (unsigned short)i1[s];
                if ((m2[s] - m1[s]) <= MARGIN) {
                    const unsigned int slot = atomicAdd(cntp, 1u);
                    if (slot < LIST_CAP) { list[slot] = (unsigned int)p; v = 0xFFFFu; }
                    // overflow (can't happen at ~1% flag rate): keep approx winner
                }
                idxb[p] = v;
            }
    }
}

// ---------------- K2: exact rescore, ONE flagged pixel per wave --------------
__global__ __launch_bounds__(64) void vq_fixup(
    const float* __restrict__ x, const float* __restrict__ cb,
    float* __restrict__ ws)
{
    const float* en2s = ws + WS_EN2 / 4;
    unsigned short* idxb = (unsigned short*)((char*)ws + WS_IDX);
    const unsigned int* list = (const unsigned int*)((const char*)ws + WS_LIST);
    unsigned int cnt = *(const unsigned int*)((const char*)ws + WS_CNT);
    if (cnt > LIST_CAP) cnt = LIST_CAP;

    const int l = threadIdx.x;           // block = 1 wave
    for (unsigned int wi = blockIdx.x; wi < cnt; wi += gridDim.x) {
        const int p  = (int)list[wi];
        const int b  = p >> 12;
        const int hw = p & 4095;
        const float xv = x[(size_t)b * (DIM * HW) + (size_t)l * HW + hw]; // dim=l
        // xsq: sequential fma chain (round-2 order)
        float xsq = 0.f;
        for (int c = 0; c < DIM; ++c) {
            const float xc = __shfl(xv, c);
            xsq = fmaf(xc, xc, xsq);
        }
        // lane handles codes l*8 .. l*8+7; 4-chain dots, round-2 op order
        float ch0[8], ch1[8], ch2[8], ch3[8];
#pragma unroll
        for (int s = 0; s < 8; ++s) { ch0[s] = ch1[s] = ch2[s] = ch3[s] = 0.f; }
        for (int c4 = 0; c4 < DIM / 4; ++c4) {
            const float x0 = __shfl(xv, 4 * c4 + 0);
            const float x1 = __shfl(xv, 4 * c4 + 1);
            const float x2 = __shfl(xv, 4 * c4 + 2);
            const float x3 = __shfl(xv, 4 * c4 + 3);
#pragma unroll
            for (int s = 0; s < 8; ++s) {
                const float4 e = *(const float4*)(cb + (l * 8 + s) * DIM + 4 * c4);
                ch0[s] = fmaf(x0, e.x, ch0[s]);
                ch1[s] = fmaf(x1, e.y, ch1[s]);
                ch2[s] = fmaf(x2, e.z, ch2[s]);
                ch3[s] = fmaf(x3, e.w, ch3[s]);
            }
        }
        float best = 3.4e38f; int bidx = 0;
#pragma unroll
        for (int s = 0; s < 8; ++s) {
            const float dot = (ch0[s] + ch1[s]) + (ch2[s] + ch3[s]);
            const float dist = fmaf(-2.f, dot, xsq) + en2s[l * 8 + s];
            if (dist < best) { best = dist; bidx = l * 8 + s; }
        }
#pragma unroll
        for (int off = 1; off < 64; off <<= 1) {
            const float bv = __shfl_xor(best, off);
            const int   bi = __shfl_xor(bidx, off);
            const bool take = (bv < best) || ((bv == best) && (bi < bidx));
            bidx = take ? bi : bidx;
            best = fminf(best, bv);
        }
        if (l == 0) idxb[p] = (unsigned short)bidx;   // resolve index only
    }
}

// ---------------- K3: gather + ST output + loss partials (ALL pixels) -------
__global__ __launch_bounds__(256, 2) void vq_epilogue(
    const float* __restrict__ x, const float* __restrict__ cb,
    float* __restrict__ out, float* __restrict__ ws)
{
    const unsigned short* idxb = (const unsigned short*)((const char*)ws + WS_IDX);
    float* bs1 = ws + WS_BS1 / 4;
    __shared__ float wsum[4];

    const int p  = blockIdx.x * 256 + threadIdx.x;
    const int b  = p >> 12;
    const int hw = p & 4095;
    const float* xp = x + (size_t)b * (DIM * HW) + hw;
    float* op       = out + (size_t)b * (DIM * HW) + hw;

    const int f = (int)idxb[p];          // always a valid code after fixup
    const float4* qrow = (const float4*)(cb + f * DIM);
    float lsum = 0.f;
#pragma unroll
    for (int c4 = 0; c4 < DIM / 4; ++c4) {
        const float4 e = qrow[c4];
        const float x0 = xp[(size_t)(4 * c4 + 0) * HW];
        const float x1 = xp[(size_t)(4 * c4 + 1) * HW];
        const float x2 = xp[(size_t)(4 * c4 + 2) * HW];
        const float x3 = xp[(size_t)(4 * c4 + 3) * HW];
        const float dx0 = e.x - x0, dx1 = e.y - x1;
        const float dx2 = e.z - x2, dx3 = e.w - x3;
        op[(size_t)(4 * c4 + 0) * HW] = x0 + dx0;   // x + (q-x), ref ST rounding
        op[(size_t)(4 * c4 + 1) * HW] = x1 + dx1;
        op[(size_t)(4 * c4 + 2) * HW] = x2 + dx2;
        op[(size_t)(4 * c4 + 3) * HW] = x3 + dx3;
        lsum = fmaf(dx0, dx0, lsum);
        lsum = fmaf(dx1, dx1, lsum);
        lsum = fmaf(dx2, dx2, lsum);
        lsum = fmaf(dx3, dx3, lsum);
    }
#pragma unroll
    for (int off = 32; off > 0; off >>= 1)
        lsum += __shfl_xor(lsum, off);
    const int wid = threadIdx.x >> 6;
    if ((threadIdx.x & 63) == 0) wsum[wid] = lsum;
    __syncthreads();
    if (threadIdx.x == 0)
        bs1[blockIdx.x] = (wsum[0] + wsum[1]) + (wsum[2] + wsum[3]);
}

// ---------------- K4: final loss (identical tree to round-2) ----------------
__global__ void vq_final(float* __restrict__ ws, float* __restrict__ lossp)
{
    const float* bs1 = ws + WS_BS1 / 4;
    float v = bs1[threadIdx.x];          // 512 threads, one partial each
#pragma unroll
    for (int off = 32; off > 0; off >>= 1)
        v += __shfl_xor(v, off);
    __shared__ float wsh[8];
    const int wid = threadIdx.x >> 6;
    if ((threadIdx.x & 63) == 0) wsh[wid] = v;
    __syncthreads();
    if (threadIdx.x == 0) {
        float s = 0.f;
#pragma unroll
        for (int i = 0; i < 8; ++i) s += wsh[i];
        const float L = s / NELEM;       // mean squared error (== both loss terms)
        *lossp = L + 0.25f * L;          // q_latent + commitment*e_latent
    }
}

extern "C" void kernel_launch(void* const* d_in, const int* in_sizes, int n_in,
                              void* d_out, int out_size, void* d_ws, size_t ws_size,
                              hipStream_t stream)
{
    const float* x  = (const float*)d_in[0];
    const float* cb = (const float*)d_in[1];
    float* out      = (float*)d_out;
    float* wsf      = (float*)d_ws;   // needs >= 659472 bytes

    vq_setup   <<<32,   256, 0, stream>>>(cb, wsf);
    vq_mfma    <<<1024, 256, 0, stream>>>(x, wsf);
    vq_fixup   <<<2048,  64, 0, stream>>>(x, cb, wsf);
    vq_epilogue<<<512,  256, 0, stream>>>(x, cb, out, wsf);
    vq_final   <<<1,    512, 0, stream>>>(wsf, out + (size_t)NPIX * DIM);
}